// Round 5
// baseline (537.627 us; speedup 1.0000x reference)
//
#include <hip/hip_runtime.h>
#include <hip/hip_bf16.h>
#include <stdint.h>

typedef float f32x4 __attribute__((ext_vector_type(4)));
typedef short s16x8 __attribute__((ext_vector_type(8)));
typedef short s16x4 __attribute__((ext_vector_type(4)));

// Compiler-known MFMA: hipcc inserts the XDL->VALU hazard nops and schedules
// lgkmcnt around the operand ds_reads (inline asm did NOT -> round-1 failure).
__device__ __forceinline__ f32x4 mfma16(s16x8 a, s16x8 b, f32x4 c) {
  return __builtin_amdgcn_mfma_f32_16x16x32_bf16(a, b, c, 0, 0, 0);
}

typedef __attribute__((address_space(3))) void lds_void;
typedef const __attribute__((address_space(1))) void gbl_void;

__device__ __forceinline__ void gload_lds16(const void* g, void* l) {
  __builtin_amdgcn_global_load_lds((gbl_void*)g, (lds_void*)l, 16, 0, 0);
}

__device__ __forceinline__ short f2bf(float f) {
  uint32_t u = __builtin_bit_cast(uint32_t, f);
  u += 0x7fffu + ((u >> 16) & 1u);
  return (short)(u >> 16);
}

// ---------------------------------------------------------------------------
// x f32 -> bf16, 4 elems/thread
__global__ __launch_bounds__(256) void k_cvt_x(const float* __restrict__ in,
                                               short* __restrict__ out) {
  const int i = blockIdx.x * 256 + threadIdx.x;
  const f32x4 v = ((const f32x4*)in)[i];
  s16x4 o;
  o[0] = f2bf(v[0]); o[1] = f2bf(v[1]); o[2] = f2bf(v[2]); o[3] = f2bf(v[3]);
  ((s16x4*)out)[i] = o;
}

// W[K][N] f32 -> Wt[N][K] bf16 (B^T layout for the GEMM)
__global__ __launch_bounds__(256) void k_transpose_w(const float* __restrict__ W,
                                                     short* __restrict__ Wt,
                                                     int K, int N) {
  __shared__ float tile[32][33];
  const int nb = blockIdx.x * 32;
  const int kb = blockIdx.y * 32;
  const int tx = threadIdx.x & 31;
  const int ty = threadIdx.x >> 5;  // 0..7
#pragma unroll
  for (int r = 0; r < 4; ++r)
    tile[ty + 8 * r][tx] = W[(size_t)(kb + ty + 8 * r) * N + nb + tx];
  __syncthreads();
#pragma unroll
  for (int r = 0; r < 4; ++r)
    Wt[(size_t)(nb + ty + 8 * r) * K + kb + tx] = f2bf(tile[tx][ty + 8 * r]);
}

// ---------------------------------------------------------------------------
// Shared GEMM mainloop: C[128x128] = A[128x512] * B^T[128x512]^T, bf16 MFMA.
// LDS tiles [128 rows][64 k] bf16 with XOR swizzle byte^=((row&7)<<4),
// staged by global_load_lds from pre-swizzled global addresses (rule #21).
__device__ __forceinline__ void gemm_mainloop_512(const short* __restrict__ Ag,
                                                  const short* __restrict__ Bg,
                                                  f32x4 acc[4][4]) {
  __shared__ char smem[32768];
  const int t = threadIdx.x;
  const int lane = t & 63;
  const int wv = t >> 6;
  const int lg = lane >> 4;
  const int l15 = lane & 15;
  const int wr = wv >> 1;
  const int wc = wv & 1;
  char* As = smem;
  char* Bs = smem + 16384;

  for (int kt = 0; kt < 8; ++kt) {
#pragma unroll
    for (int i = 0; i < 4; ++i) {
      const int p = (i * 256 + t) * 16;                 // linear LDS byte pos
      const int row = p >> 7;                           // 128B rows (64 bf16)
      const int kb = (p & 127) ^ ((row & 7) << 4);      // inverse swizzle on src
      gload_lds16((const char*)Ag + (size_t)row * 1024 + kt * 128 + kb,
                  As + i * 4096 + wv * 1024);
      gload_lds16((const char*)Bg + (size_t)row * 1024 + kt * 128 + kb,
                  Bs + i * 4096 + wv * 1024);
    }
    __syncthreads();  // compiler drains vmcnt before s_barrier (m97 behavior)
#pragma unroll
    for (int ks = 0; ks < 2; ++ks) {
      s16x8 a[4], b[4];
#pragma unroll
      for (int f = 0; f < 4; ++f) {
        const int ra = wr * 64 + f * 16 + l15;
        a[f] = *(const s16x8*)(As + ra * 128 +
                               ((ks * 64 + lg * 16) ^ ((ra & 7) << 4)));
      }
#pragma unroll
      for (int f = 0; f < 4; ++f) {
        const int rb = wc * 64 + f * 16 + l15;
        b[f] = *(const s16x8*)(Bs + rb * 128 +
                               ((ks * 64 + lg * 16) ^ ((rb & 7) << 4)));
      }
#pragma unroll
      for (int fm = 0; fm < 4; ++fm)
#pragma unroll
        for (int fn = 0; fn < 4; ++fn)
          acc[fm][fn] = mfma16(a[fm], b[fn], acc[fm][fn]);
    }
    __syncthreads();
  }
}

// ---------------------------------------------------------------------------
// QKV projection GEMM, linear grid 6144 with bijective XCD-chunk swizzle:
// all 12 bn-blocks of one bm run on the SAME XCD -> A-tile L2-resident (T1).
// bn 0..3 -> Q, 4..7 -> K, 8..11 -> V. Scatter-store into [b][h][n][d] bf16.
__global__ __launch_bounds__(256) void k_gemm_qkv(
    const short* __restrict__ xb, const short* __restrict__ Wqt,
    const short* __restrict__ Wkvt, const float* __restrict__ bq,
    const float* __restrict__ bkv, short* __restrict__ Qb,
    short* __restrict__ Kb, short* __restrict__ Vb) {
  const int bid = blockIdx.x;                 // 0..6143, xcd ~ bid%8
  const int orig = (bid & 7) * 768 + (bid >> 3);  // chunk of 768 per XCD
  const int bm = orig / 12;                   // 0..511
  const int bn = orig % 12;                   // 0..11, consecutive on one XCD
  f32x4 acc[4][4];
  const f32x4 z = {0.f, 0.f, 0.f, 0.f};
  for (int i = 0; i < 4; ++i)
    for (int j = 0; j < 4; ++j) acc[i][j] = z;

  const short* Ag = xb + (size_t)bm * 128 * 512;
  const short* Bg = (bn < 4) ? (Wqt + (size_t)bn * 128 * 512)
                             : (Wkvt + (size_t)(bn - 4) * 128 * 512);
  gemm_mainloop_512(Ag, Bg, acc);

  const int t = threadIdx.x, lane = t & 63, wv = t >> 6;
  const int lg = lane >> 4, l15 = lane & 15;
  const int wr = wv >> 1, wc = wv & 1;
  const int m0 = bm * 128 + wr * 64;
  const int n0 = bn * 128 + wc * 64;

  short* dst; int nsub; const float* bias; int bsub;
  if (bn < 4)      { dst = Qb; nsub = 0;    bias = bq;  bsub = 0; }
  else if (bn < 8) { dst = Kb; nsub = 512;  bias = bkv; bsub = 512; }
  else             { dst = Vb; nsub = 1024; bias = bkv; bsub = 512; }

#pragma unroll
  for (int fm = 0; fm < 4; ++fm)
#pragma unroll
    for (int fn = 0; fn < 4; ++fn)
#pragma unroll
      for (int j = 0; j < 4; ++j) {
        const int m = m0 + fm * 16 + lg * 4 + j;   // C/D: row=(lane>>4)*4+reg
        const int n = n0 + fn * 16 + l15;          //      col=lane&15
        const float v = acc[fm][fn][j] + bias[n - bsub];
        const int c = n - nsub;
        const int h = c >> 5, d = c & 31;
        const int b = m >> 6, nr = m & 63;
        dst[((size_t)(b * 16 + h) * 64 + nr) * 32 + d] = f2bf(v);
      }
}

// ---------------------------------------------------------------------------
// Attention: one block (256 thr, 4 waves) per (window b, head h).
// S = scale*Q K^T + mask; P = softmax(S); O = P V.  N=64, D=32.
__global__ __launch_bounds__(256) void k_attn(
    const short* __restrict__ Qb, const short* __restrict__ Kb,
    const short* __restrict__ Vb, const float* __restrict__ mask,
    short* __restrict__ AO) {
  __shared__ char vt[4096];  // V^T [d=32][m=64] bf16, swizzled
  __shared__ char pb[8192];  // per-wave P [16][64] bf16, swizzled
  const int gid = blockIdx.x;          // b*16 + h
  const int b = gid >> 4, h = gid & 15;
  const int t = threadIdx.x, lane = t & 63, wv = t >> 6;
  const int lg = lane >> 4, l15 = lane & 15;
  const short* qg = Qb + (size_t)gid * 2048;
  const short* kg = Kb + (size_t)gid * 2048;
  const short* vg = Vb + (size_t)gid * 2048;

  // stage V transposed + swizzled into LDS
  {
    const s16x8 vv = *(const s16x8*)(vg + t * 8);
    const int m = t >> 2, d0 = (t & 3) * 8;
#pragma unroll
    for (int j = 0; j < 8; ++j) {
      const int d = d0 + j;
      *(short*)(vt + d * 128 + ((2 * m) ^ ((d & 7) << 4))) = vv[j];
    }
  }

  // QK^T: wave wv owns S rows [wv*16, wv*16+16). Operands direct from global.
  const s16x8 qf = *(const s16x8*)(qg + (wv * 16 + l15) * 32 + lg * 8);
  f32x4 s[4];
  const f32x4 z = {0.f, 0.f, 0.f, 0.f};
#pragma unroll
  for (int fn = 0; fn < 4; ++fn) {
    const s16x8 kf = *(const s16x8*)(kg + (fn * 16 + l15) * 32 + lg * 8);
    s[fn] = mfma16(qf, kf, z);
  }

  // softmax (wave-parallel, 16-lane-group shuffle reductions)
  const float scale = 0.17677669529663687f;  // 1/sqrt(32)
  const float* mrow = mask + (size_t)(b & 255) * 4096;
  float sv[4][4];
#pragma unroll
  for (int fn = 0; fn < 4; ++fn)
#pragma unroll
    for (int j = 0; j < 4; ++j)
      sv[fn][j] = s[fn][j] * scale +
                  mrow[(wv * 16 + lg * 4 + j) * 64 + fn * 16 + l15];
#pragma unroll
  for (int j = 0; j < 4; ++j) {
    float mx = fmaxf(fmaxf(sv[0][j], sv[1][j]), fmaxf(sv[2][j], sv[3][j]));
#pragma unroll
    for (int off = 1; off < 16; off <<= 1) mx = fmaxf(mx, __shfl_xor(mx, off));
    float sum = 0.f;
#pragma unroll
    for (int fn = 0; fn < 4; ++fn) {
      sv[fn][j] = __expf(sv[fn][j] - mx);
      sum += sv[fn][j];
    }
#pragma unroll
    for (int off = 1; off < 16; off <<= 1) sum += __shfl_xor(sum, off);
    const float inv = 1.f / sum;
#pragma unroll
    for (int fn = 0; fn < 4; ++fn) sv[fn][j] *= inv;
  }

  // P -> per-wave LDS (bf16, swizzled)
  char* pw = pb + wv * 2048;
#pragma unroll
  for (int fn = 0; fn < 4; ++fn)
#pragma unroll
    for (int j = 0; j < 4; ++j) {
      const int row = lg * 4 + j;
      const int col = fn * 16 + l15;
      *(short*)(pw + row * 128 + ((col * 2) ^ ((row & 7) << 4))) =
          f2bf(sv[fn][j]);
    }

  __syncthreads();  // vt visible to all waves; P ds_writes drained

  // O = P @ V  (K=64 -> 2 k-steps; output 16x32 per wave)
  f32x4 o[2];
  o[0] = z; o[1] = z;
#pragma unroll
  for (int ks = 0; ks < 2; ++ks) {
    const s16x8 pa = *(const s16x8*)(pw + l15 * 128 +
                                     ((ks * 64 + lg * 16) ^ ((l15 & 7) << 4)));
#pragma unroll
    for (int fd = 0; fd < 2; ++fd) {
      const int d = fd * 16 + l15;
      const s16x8 vb = *(const s16x8*)(vt + d * 128 +
                                       ((ks * 64 + lg * 16) ^ ((d & 7) << 4)));
      o[fd] = mfma16(pa, vb, o[fd]);
    }
  }

  // AO[b*64+row][h*32+d] bf16
#pragma unroll
  for (int fd = 0; fd < 2; ++fd)
#pragma unroll
    for (int j = 0; j < 4; ++j) {
      const int row = wv * 16 + lg * 4 + j;
      const int d = fd * 16 + l15;
      AO[((size_t)(b * 64 + row)) * 512 + h * 32 + d] = f2bf(o[fd][j]);
    }
}

// ---------------------------------------------------------------------------
// Output projection: out[m][n] = AO[m][:] . Wp[:][n] + bp[n], f32 out.
// Linear grid 2048 with XCD-chunk swizzle: 4 bn-blocks of one bm per XCD.
__global__ __launch_bounds__(256) void k_gemm_proj(
    const short* __restrict__ AO, const short* __restrict__ Wpt,
    const float* __restrict__ bp, float* __restrict__ out) {
  const int bid = blockIdx.x;                 // 0..2047
  const int orig = (bid & 7) * 256 + (bid >> 3);  // chunk of 256 per XCD
  const int bm = orig >> 2;                   // 0..511
  const int bn = orig & 3;                    // 0..3
  f32x4 acc[4][4];
  const f32x4 z = {0.f, 0.f, 0.f, 0.f};
  for (int i = 0; i < 4; ++i)
    for (int j = 0; j < 4; ++j) acc[i][j] = z;

  gemm_mainloop_512(AO + (size_t)bm * 65536, Wpt + (size_t)bn * 65536, acc);

  const int t = threadIdx.x, lane = t & 63, wv = t >> 6;
  const int lg = lane >> 4, l15 = lane & 15;
  const int wr = wv >> 1, wc = wv & 1;
  const int m0 = bm * 128 + wr * 64;
  const int n0 = bn * 128 + wc * 64;
#pragma unroll
  for (int fm = 0; fm < 4; ++fm)
#pragma unroll
    for (int fn = 0; fn < 4; ++fn)
#pragma unroll
      for (int j = 0; j < 4; ++j) {
        const int m = m0 + fm * 16 + lg * 4 + j;
        const int n = n0 + fn * 16 + l15;
        out[(size_t)m * 512 + n] = acc[fm][fn][j] + bp[n];
      }
}

// ---------------------------------------------------------------------------
extern "C" void kernel_launch(void* const* d_in, const int* in_sizes, int n_in,
                              void* d_out, int out_size, void* d_ws,
                              size_t ws_size, hipStream_t stream) {
  const float* x    = (const float*)d_in[0];
  const float* mask = (const float*)d_in[1];
  const float* Wq   = (const float*)d_in[2];
  const float* bq   = (const float*)d_in[3];
  const float* Wkv  = (const float*)d_in[4];
  const float* bkv  = (const float*)d_in[5];
  const float* Wp   = (const float*)d_in[6];
  const float* bp   = (const float*)d_in[7];
  float* out = (float*)d_out;
  char* ws = (char*)d_ws;

  // workspace layout (bytes); AO aliases xb (xb dead after k_gemm_qkv)
  short* xb   = (short*)(ws);                       // 64 MB
  short* Wqt  = (short*)(ws + 67108864);            // 0.5 MB
  short* Wkvt = (short*)(ws + 67108864 + 524288);   // 1 MB
  short* Wpt  = (short*)(ws + 67108864 + 1572864);  // 0.5 MB
  short* Qb   = (short*)(ws + 69206016);            // 64 MB
  short* Kb   = (short*)(ws + 69206016 + 67108864);          // 64 MB
  short* Vb   = (short*)(ws + 69206016 + 2 * 67108864);      // 64 MB
  short* AO   = xb;

  k_cvt_x<<<dim3(32768), dim3(256), 0, stream>>>(x, xb);
  k_transpose_w<<<dim3(16, 16), dim3(256), 0, stream>>>(Wq, Wqt, 512, 512);
  k_transpose_w<<<dim3(32, 16), dim3(256), 0, stream>>>(Wkv, Wkvt, 512, 1024);
  k_transpose_w<<<dim3(16, 16), dim3(256), 0, stream>>>(Wp, Wpt, 512, 512);
  k_gemm_qkv<<<dim3(6144), dim3(256), 0, stream>>>(xb, Wqt, Wkvt, bq, bkv,
                                                   Qb, Kb, Vb);
  k_attn<<<dim3(16384), dim3(256), 0, stream>>>(Qb, Kb, Vb, mask, AO);
  k_gemm_proj<<<dim3(2048), dim3(256), 0, stream>>>(AO, Wpt, bp, out);
}

// Round 6
// 492.231 us; speedup vs baseline: 1.0922x; 1.0922x over previous
//
#include <hip/hip_runtime.h>
#include <hip/hip_bf16.h>
#include <stdint.h>

typedef float f32x4 __attribute__((ext_vector_type(4)));
typedef short s16x8 __attribute__((ext_vector_type(8)));
typedef short s16x4 __attribute__((ext_vector_type(4)));

// Compiler-known MFMA: hipcc inserts the XDL->VALU hazard nops and schedules
// lgkmcnt around the operand ds_reads (inline asm did NOT -> round-1 failure).
__device__ __forceinline__ f32x4 mfma16(s16x8 a, s16x8 b, f32x4 c) {
  return __builtin_amdgcn_mfma_f32_16x16x32_bf16(a, b, c, 0, 0, 0);
}

typedef __attribute__((address_space(3))) void lds_void;
typedef const __attribute__((address_space(1))) void gbl_void;

__device__ __forceinline__ void gload_lds16(const void* g, void* l) {
  __builtin_amdgcn_global_load_lds((gbl_void*)g, (lds_void*)l, 16, 0, 0);
}

__device__ __forceinline__ short f2bf(float f) {
  uint32_t u = __builtin_bit_cast(uint32_t, f);
  u += 0x7fffu + ((u >> 16) & 1u);
  return (short)(u >> 16);
}

// ---------------------------------------------------------------------------
// x f32 -> bf16, 4 elems/thread
__global__ __launch_bounds__(256) void k_cvt_x(const float* __restrict__ in,
                                               short* __restrict__ out) {
  const int i = blockIdx.x * 256 + threadIdx.x;
  const f32x4 v = ((const f32x4*)in)[i];
  s16x4 o;
  o[0] = f2bf(v[0]); o[1] = f2bf(v[1]); o[2] = f2bf(v[2]); o[3] = f2bf(v[3]);
  ((s16x4*)out)[i] = o;
}

// W[K][N] f32 -> Wt[N][K] bf16 (B^T layout for the GEMM)
__global__ __launch_bounds__(256) void k_transpose_w(const float* __restrict__ W,
                                                     short* __restrict__ Wt,
                                                     int K, int N) {
  __shared__ float tile[32][33];
  const int nb = blockIdx.x * 32;
  const int kb = blockIdx.y * 32;
  const int tx = threadIdx.x & 31;
  const int ty = threadIdx.x >> 5;  // 0..7
#pragma unroll
  for (int r = 0; r < 4; ++r)
    tile[ty + 8 * r][tx] = W[(size_t)(kb + ty + 8 * r) * N + nb + tx];
  __syncthreads();
#pragma unroll
  for (int r = 0; r < 4; ++r)
    Wt[(size_t)(nb + ty + 8 * r) * K + kb + tx] = f2bf(tile[tx][ty + 8 * r]);
}

// ---------------------------------------------------------------------------
// Shared GEMM mainloop: C[128x128] = A[128x512] * B^T[128x512]^T, bf16 MFMA.
// T3-minimum pipeline: 2 LDS slots (32 KB each); STAGE(next tile, other slot)
// issued BEFORE compute of current slot; ONE __syncthreads per K-tile whose
// implicit vmcnt(0) drain retires the prefetch. Tile kt+1's HBM/L2 latency
// overlaps tile kt's ds_read+MFMA. Swizzle: byte^=((row&7)<<4), applied as
// inverse on the global source (rule #21: gload_lds dest must stay linear).
__device__ __forceinline__ void gemm_mainloop_512(const short* __restrict__ Ag,
                                                  const short* __restrict__ Bg,
                                                  f32x4 acc[4][4]) {
  __shared__ char smem[65536];  // [2 slots][A 16KB | B 16KB]
  const int t = threadIdx.x;
  const int lane = t & 63;
  const int wv = t >> 6;
  const int lg = lane >> 4;
  const int l15 = lane & 15;
  const int wr = wv >> 1;
  const int wc = wv & 1;

#define STAGE_TILE(slot, kt)                                                  \
  {                                                                           \
    char* base_ = smem + (slot) * 32768;                                      \
    _Pragma("unroll") for (int i_ = 0; i_ < 4; ++i_) {                        \
      const int p_ = (i_ * 256 + t) * 16;                                     \
      const int row_ = p_ >> 7;                                               \
      const int kb_ = (p_ & 127) ^ ((row_ & 7) << 4);                         \
      gload_lds16((const char*)Ag + (size_t)row_ * 1024 + (kt) * 128 + kb_,   \
                  base_ + i_ * 4096 + wv * 1024);                             \
      gload_lds16((const char*)Bg + (size_t)row_ * 1024 + (kt) * 128 + kb_,   \
                  base_ + 16384 + i_ * 4096 + wv * 1024);                     \
    }                                                                         \
  }

  STAGE_TILE(0, 0);
  __syncthreads();  // tile 0 resident (vmcnt drained by barrier semantics)

  for (int kt = 0; kt < 8; ++kt) {
    const int s = kt & 1;
    if (kt < 7) STAGE_TILE(s ^ 1, kt + 1);  // async prefetch into other slot
    const char* As = smem + s * 32768;
    const char* Bs = As + 16384;
#pragma unroll
    for (int ks = 0; ks < 2; ++ks) {
      s16x8 a[4], b[4];
#pragma unroll
      for (int f = 0; f < 4; ++f) {
        const int ra = wr * 64 + f * 16 + l15;
        a[f] = *(const s16x8*)(As + ra * 128 +
                               ((ks * 64 + lg * 16) ^ ((ra & 7) << 4)));
      }
#pragma unroll
      for (int f = 0; f < 4; ++f) {
        const int rb = wc * 64 + f * 16 + l15;
        b[f] = *(const s16x8*)(Bs + rb * 128 +
                               ((ks * 64 + lg * 16) ^ ((rb & 7) << 4)));
      }
#pragma unroll
      for (int fm = 0; fm < 4; ++fm)
#pragma unroll
        for (int fn = 0; fn < 4; ++fn)
          acc[fm][fn] = mfma16(a[fm], b[fn], acc[fm][fn]);
    }
    // Single barrier per K-tile: drains vmcnt (prefetch landed) + lgkm, and
    // guarantees all waves done reading slot s before it is re-staged at kt+2.
    __syncthreads();
  }
#undef STAGE_TILE
}

// ---------------------------------------------------------------------------
// QKV projection GEMM, linear grid 6144 with bijective XCD-chunk swizzle:
// all 12 bn-blocks of one bm run on the SAME XCD -> A-tile L2-resident (T1).
// bn 0..3 -> Q, 4..7 -> K, 8..11 -> V. Scatter-store into [b][h][n][d] bf16.
__global__ __launch_bounds__(256) void k_gemm_qkv(
    const short* __restrict__ xb, const short* __restrict__ Wqt,
    const short* __restrict__ Wkvt, const float* __restrict__ bq,
    const float* __restrict__ bkv, short* __restrict__ Qb,
    short* __restrict__ Kb, short* __restrict__ Vb) {
  const int bid = blockIdx.x;                 // 0..6143, xcd ~ bid%8
  const int orig = (bid & 7) * 768 + (bid >> 3);  // chunk of 768 per XCD
  const int bm = orig / 12;                   // 0..511
  const int bn = orig % 12;                   // 0..11, consecutive on one XCD
  f32x4 acc[4][4];
  const f32x4 z = {0.f, 0.f, 0.f, 0.f};
  for (int i = 0; i < 4; ++i)
    for (int j = 0; j < 4; ++j) acc[i][j] = z;

  const short* Ag = xb + (size_t)bm * 128 * 512;
  const short* Bg = (bn < 4) ? (Wqt + (size_t)bn * 128 * 512)
                             : (Wkvt + (size_t)(bn - 4) * 128 * 512);
  gemm_mainloop_512(Ag, Bg, acc);

  const int t = threadIdx.x, lane = t & 63, wv = t >> 6;
  const int lg = lane >> 4, l15 = lane & 15;
  const int wr = wv >> 1, wc = wv & 1;
  const int m0 = bm * 128 + wr * 64;
  const int n0 = bn * 128 + wc * 64;

  short* dst; int nsub; const float* bias; int bsub;
  if (bn < 4)      { dst = Qb; nsub = 0;    bias = bq;  bsub = 0; }
  else if (bn < 8) { dst = Kb; nsub = 512;  bias = bkv; bsub = 512; }
  else             { dst = Vb; nsub = 1024; bias = bkv; bsub = 512; }

#pragma unroll
  for (int fm = 0; fm < 4; ++fm)
#pragma unroll
    for (int fn = 0; fn < 4; ++fn)
#pragma unroll
      for (int j = 0; j < 4; ++j) {
        const int m = m0 + fm * 16 + lg * 4 + j;   // C/D: row=(lane>>4)*4+reg
        const int n = n0 + fn * 16 + l15;          //      col=lane&15
        const float v = acc[fm][fn][j] + bias[n - bsub];
        const int c = n - nsub;
        const int h = c >> 5, d = c & 31;
        const int b = m >> 6, nr = m & 63;
        dst[((size_t)(b * 16 + h) * 64 + nr) * 32 + d] = f2bf(v);
      }
}

// ---------------------------------------------------------------------------
// Attention: one block (256 thr, 4 waves) per (window b, head h).
// S = scale*Q K^T + mask; P = softmax(S); O = P V.  N=64, D=32.
__global__ __launch_bounds__(256) void k_attn(
    const short* __restrict__ Qb, const short* __restrict__ Kb,
    const short* __restrict__ Vb, const float* __restrict__ mask,
    short* __restrict__ AO) {
  __shared__ char vt[4096];  // V^T [d=32][m=64] bf16, swizzled
  __shared__ char pb[8192];  // per-wave P [16][64] bf16, swizzled
  const int gid = blockIdx.x;          // b*16 + h
  const int b = gid >> 4, h = gid & 15;
  const int t = threadIdx.x, lane = t & 63, wv = t >> 6;
  const int lg = lane >> 4, l15 = lane & 15;
  const short* qg = Qb + (size_t)gid * 2048;
  const short* kg = Kb + (size_t)gid * 2048;
  const short* vg = Vb + (size_t)gid * 2048;

  // stage V transposed + swizzled into LDS
  {
    const s16x8 vv = *(const s16x8*)(vg + t * 8);
    const int m = t >> 2, d0 = (t & 3) * 8;
#pragma unroll
    for (int j = 0; j < 8; ++j) {
      const int d = d0 + j;
      *(short*)(vt + d * 128 + ((2 * m) ^ ((d & 7) << 4))) = vv[j];
    }
  }

  // QK^T: wave wv owns S rows [wv*16, wv*16+16). Operands direct from global.
  const s16x8 qf = *(const s16x8*)(qg + (wv * 16 + l15) * 32 + lg * 8);
  f32x4 s[4];
  const f32x4 z = {0.f, 0.f, 0.f, 0.f};
#pragma unroll
  for (int fn = 0; fn < 4; ++fn) {
    const s16x8 kf = *(const s16x8*)(kg + (fn * 16 + l15) * 32 + lg * 8);
    s[fn] = mfma16(qf, kf, z);
  }

  // softmax (wave-parallel, 16-lane-group shuffle reductions)
  const float scale = 0.17677669529663687f;  // 1/sqrt(32)
  const float* mrow = mask + (size_t)(b & 255) * 4096;
  float sv[4][4];
#pragma unroll
  for (int fn = 0; fn < 4; ++fn)
#pragma unroll
    for (int j = 0; j < 4; ++j)
      sv[fn][j] = s[fn][j] * scale +
                  mrow[(wv * 16 + lg * 4 + j) * 64 + fn * 16 + l15];
#pragma unroll
  for (int j = 0; j < 4; ++j) {
    float mx = fmaxf(fmaxf(sv[0][j], sv[1][j]), fmaxf(sv[2][j], sv[3][j]));
#pragma unroll
    for (int off = 1; off < 16; off <<= 1) mx = fmaxf(mx, __shfl_xor(mx, off));
    float sum = 0.f;
#pragma unroll
    for (int fn = 0; fn < 4; ++fn) {
      sv[fn][j] = __expf(sv[fn][j] - mx);
      sum += sv[fn][j];
    }
#pragma unroll
    for (int off = 1; off < 16; off <<= 1) sum += __shfl_xor(sum, off);
    const float inv = 1.f / sum;
#pragma unroll
    for (int fn = 0; fn < 4; ++fn) sv[fn][j] *= inv;
  }

  // P -> per-wave LDS (bf16, swizzled)
  char* pw = pb + wv * 2048;
#pragma unroll
  for (int fn = 0; fn < 4; ++fn)
#pragma unroll
    for (int j = 0; j < 4; ++j) {
      const int row = lg * 4 + j;
      const int col = fn * 16 + l15;
      *(short*)(pw + row * 128 + ((col * 2) ^ ((row & 7) << 4))) =
          f2bf(sv[fn][j]);
    }

  __syncthreads();  // vt visible to all waves; P ds_writes drained

  // O = P @ V  (K=64 -> 2 k-steps; output 16x32 per wave)
  f32x4 o[2];
  o[0] = z; o[1] = z;
#pragma unroll
  for (int ks = 0; ks < 2; ++ks) {
    const s16x8 pa = *(const s16x8*)(pw + l15 * 128 +
                                     ((ks * 64 + lg * 16) ^ ((l15 & 7) << 4)));
#pragma unroll
    for (int fd = 0; fd < 2; ++fd) {
      const int d = fd * 16 + l15;
      const s16x8 vb = *(const s16x8*)(vt + d * 128 +
                                       ((ks * 64 + lg * 16) ^ ((d & 7) << 4)));
      o[fd] = mfma16(pa, vb, o[fd]);
    }
  }

  // AO[b*64+row][h*32+d] bf16
#pragma unroll
  for (int fd = 0; fd < 2; ++fd)
#pragma unroll
    for (int j = 0; j < 4; ++j) {
      const int row = wv * 16 + lg * 4 + j;
      const int d = fd * 16 + l15;
      AO[((size_t)(b * 64 + row)) * 512 + h * 32 + d] = f2bf(o[fd][j]);
    }
}

// ---------------------------------------------------------------------------
// Output projection: out[m][n] = AO[m][:] . Wp[:][n] + bp[n], f32 out.
// Linear grid 2048 with XCD-chunk swizzle: 4 bn-blocks of one bm per XCD.
__global__ __launch_bounds__(256) void k_gemm_proj(
    const short* __restrict__ AO, const short* __restrict__ Wpt,
    const float* __restrict__ bp, float* __restrict__ out) {
  const int bid = blockIdx.x;                 // 0..2047
  const int orig = (bid & 7) * 256 + (bid >> 3);  // chunk of 256 per XCD
  const int bm = orig >> 2;                   // 0..511
  const int bn = orig & 3;                    // 0..3
  f32x4 acc[4][4];
  const f32x4 z = {0.f, 0.f, 0.f, 0.f};
  for (int i = 0; i < 4; ++i)
    for (int j = 0; j < 4; ++j) acc[i][j] = z;

  gemm_mainloop_512(AO + (size_t)bm * 65536, Wpt + (size_t)bn * 65536, acc);

  const int t = threadIdx.x, lane = t & 63, wv = t >> 6;
  const int lg = lane >> 4, l15 = lane & 15;
  const int wr = wv >> 1, wc = wv & 1;
  const int m0 = bm * 128 + wr * 64;
  const int n0 = bn * 128 + wc * 64;
#pragma unroll
  for (int fm = 0; fm < 4; ++fm)
#pragma unroll
    for (int fn = 0; fn < 4; ++fn)
#pragma unroll
      for (int j = 0; j < 4; ++j) {
        const int m = m0 + fm * 16 + lg * 4 + j;
        const int n = n0 + fn * 16 + l15;
        out[(size_t)m * 512 + n] = acc[fm][fn][j] + bp[n];
      }
}

// ---------------------------------------------------------------------------
extern "C" void kernel_launch(void* const* d_in, const int* in_sizes, int n_in,
                              void* d_out, int out_size, void* d_ws,
                              size_t ws_size, hipStream_t stream) {
  const float* x    = (const float*)d_in[0];
  const float* mask = (const float*)d_in[1];
  const float* Wq   = (const float*)d_in[2];
  const float* bq   = (const float*)d_in[3];
  const float* Wkv  = (const float*)d_in[4];
  const float* bkv  = (const float*)d_in[5];
  const float* Wp   = (const float*)d_in[6];
  const float* bp   = (const float*)d_in[7];
  float* out = (float*)d_out;
  char* ws = (char*)d_ws;

  // workspace layout (bytes); AO aliases xb (xb dead after k_gemm_qkv)
  short* xb   = (short*)(ws);                       // 64 MB
  short* Wqt  = (short*)(ws + 67108864);            // 0.5 MB
  short* Wkvt = (short*)(ws + 67108864 + 524288);   // 1 MB
  short* Wpt  = (short*)(ws + 67108864 + 1572864);  // 0.5 MB
  short* Qb   = (short*)(ws + 69206016);            // 64 MB
  short* Kb   = (short*)(ws + 69206016 + 67108864);          // 64 MB
  short* Vb   = (short*)(ws + 69206016 + 2 * 67108864);      // 64 MB
  short* AO   = xb;

  k_cvt_x<<<dim3(32768), dim3(256), 0, stream>>>(x, xb);
  k_transpose_w<<<dim3(16, 16), dim3(256), 0, stream>>>(Wq, Wqt, 512, 512);
  k_transpose_w<<<dim3(32, 16), dim3(256), 0, stream>>>(Wkv, Wkvt, 512, 1024);
  k_transpose_w<<<dim3(16, 16), dim3(256), 0, stream>>>(Wp, Wpt, 512, 512);
  k_gemm_qkv<<<dim3(6144), dim3(256), 0, stream>>>(xb, Wqt, Wkvt, bq, bkv,
                                                   Qb, Kb, Vb);
  k_attn<<<dim3(16384), dim3(256), 0, stream>>>(Qb, Kb, Vb, mask, AO);
  k_gemm_proj<<<dim3(2048), dim3(256), 0, stream>>>(AO, Wpt, bp, out);
}